// Round 8
// baseline (230.721 us; speedup 1.0000x reference)
//
#include <hip/hip_runtime.h>

#define SEQ   2048
#define HID   1024
#define NHEAD 16
#define DH    64
#define S2    1024

typedef short bf16x8 __attribute__((ext_vector_type(8)));
typedef float f32x4  __attribute__((ext_vector_type(4)));

static __device__ __forceinline__ short f2bf(float f) {
    unsigned u = __float_as_uint(f);
    unsigned r = (u + 0x7fffu + ((u >> 16) & 1u)) >> 16;
    return (short)r;
}
static __device__ __forceinline__ float bf2f(short h) {
    return __uint_as_float(((unsigned)(unsigned short)h) << 16);
}
// window base: 8-aligned, covers clip([a, a+63]) within [base, base+71]
static __device__ __forceinline__ int wbase(int a) {
    int b = a < 0 ? 0 : (a > 952 ? 952 : a);
    return b & ~7;
}

// ---------------- fp32 -> bf16 conversion ----------------
__global__ __launch_bounds__(256) void cvt_bf16_k(const float* __restrict__ in,
                                                  short* __restrict__ out, int n8) {
    int idx = blockIdx.x * 256 + threadIdx.x;
    if (idx < n8) {
        const float4 a = ((const float4*)in)[idx * 2];
        const float4 b = ((const float4*)in)[idx * 2 + 1];
        bf16x8 r;
        r[0] = f2bf(a.x); r[1] = f2bf(a.y); r[2] = f2bf(a.z); r[3] = f2bf(a.w);
        r[4] = f2bf(b.x); r[5] = f2bf(b.y); r[6] = f2bf(b.z); r[7] = f2bf(b.w);
        ((bf16x8*)out)[idx] = r;
    }
}

// three equal-size 1M-element converts in one launch (rel, W_pos, W_posq)
__global__ __launch_bounds__(256) void cvt3_bf16_k(
    const float* __restrict__ in0, const float* __restrict__ in1, const float* __restrict__ in2,
    short* __restrict__ out0, short* __restrict__ out1, short* __restrict__ out2) {
    int b = blockIdx.x, sel = b >> 9;
    int idx = (b & 511) * 256 + threadIdx.x;
    const float* in = sel == 0 ? in0 : (sel == 1 ? in1 : in2);
    short* out = sel == 0 ? out0 : (sel == 1 ? out1 : out2);
    const float4 a = ((const float4*)in)[idx * 2];
    const float4 b4 = ((const float4*)in)[idx * 2 + 1];
    bf16x8 r;
    r[0] = f2bf(a.x); r[1] = f2bf(a.y); r[2] = f2bf(a.z); r[3] = f2bf(a.w);
    r[4] = f2bf(b4.x); r[5] = f2bf(b4.y); r[6] = f2bf(b4.z); r[7] = f2bf(b4.w);
    ((bf16x8*)out)[idx] = r;
}

// ---------------- mask tile flags: 0 all-zero, 1 mixed, 2 all-ones ----------------
__global__ __launch_bounds__(256) void maskflag_k(const int* __restrict__ amask, int* __restrict__ flags)
{
    __shared__ int sall[4], sany[4];
    const int jt = blockIdx.x, it = blockIdx.y;
    const int tid = threadIdx.x;
    const int r = tid >> 2, cseg = (tid & 3) << 4;
    const int4* rp = (const int4*)(amask + (size_t)(it * 64 + r) * SEQ + jt * 64 + cseg);
    int allnz = 1, anynz = 0;
    #pragma unroll
    for (int e = 0; e < 4; ++e) {
        int4 v = rp[e];
        allnz &= (v.x != 0) & (v.y != 0) & (v.z != 0) & (v.w != 0);
        anynz |= (v.x != 0) | (v.y != 0) | (v.z != 0) | (v.w != 0);
    }
    unsigned long long ba = __ballot(allnz != 0);
    unsigned long long bo = __ballot(anynz != 0);
    const int w = tid >> 6;
    if ((tid & 63) == 0) { sall[w] = (ba == ~0ull); sany[w] = (bo != 0ull); }
    __syncthreads();
    if (tid == 0) {
        int all4 = sall[0] & sall[1] & sall[2] & sall[3];
        int any4 = sany[0] | sany[1] | sany[2] | sany[3];
        flags[it * 32 + jt] = all4 ? 2 : (any4 ? 1 : 0);
    }
}

// ---------------- shared MFMA GEMM core: C[128x64] += A[128xK] * B[64xK]^T ----------------
static __device__ __forceinline__ void gemm_tile(
    const short* __restrict__ Ag, int lda,
    const short* __restrict__ Bg, int ldb,
    int K, short* As, short* Bs, f32x4 (&acc)[4][2])
{
    const int tid = threadIdx.x;
    const int lane = tid & 63, w = tid >> 6;
    const int g = lane >> 4, ln = lane & 15;
    const int wm = (w >> 1) * 64, wn = (w & 1) * 32;
    for (int kt = 0; kt < K; kt += 64) {
        __syncthreads();
        #pragma unroll
        for (int it = 0; it < 4; ++it) {
            int c = it * 256 + tid;
            int r = c >> 3, cb = c & 7;
            uint4 v = *(const uint4*)(Ag + (size_t)r * lda + kt + ((cb ^ (r & 7)) << 3));
            *(uint4*)(As + r * 64 + cb * 8) = v;
        }
        #pragma unroll
        for (int it = 0; it < 2; ++it) {
            int c = it * 256 + tid;
            int r = c >> 3, cb = c & 7;
            uint4 v = *(const uint4*)(Bg + (size_t)r * ldb + kt + ((cb ^ (r & 7)) << 3));
            *(uint4*)(Bs + r * 64 + cb * 8) = v;
        }
        __syncthreads();
        #pragma unroll
        for (int k0 = 0; k0 < 2; ++k0) {
            bf16x8 bfr[2];
            #pragma unroll
            for (int nf = 0; nf < 2; ++nf) {
                int rr = wn + nf * 16 + ln;
                int kc = (k0 * 4 + g) ^ (rr & 7);
                bfr[nf] = *(const bf16x8*)(Bs + rr * 64 + kc * 8);
            }
            #pragma unroll
            for (int mf = 0; mf < 4; ++mf) {
                int rr = wm + mf * 16 + ln;
                int kc = (k0 * 4 + g) ^ (rr & 7);
                bf16x8 afr = *(const bf16x8*)(As + rr * 64 + kc * 8);
                #pragma unroll
                for (int nf = 0; nf < 2; ++nf)
                    acc[mf][nf] = __builtin_amdgcn_mfma_f32_16x16x32_bf16(afr, bfr[nf], acc[mf][nf], 0, 0, 0);
            }
        }
    }
}

// ---------------- QKV projection ----------------
__global__ __launch_bounds__(256) void qkv_mfma_k(
    const short* __restrict__ hid, const short* __restrict__ win,
    const float* __restrict__ q_bias, const float* __restrict__ v_bias,
    short* __restrict__ qT, short* __restrict__ kT, short* __restrict__ vT)
{
    __shared__ __align__(16) short As[128 * 64];
    __shared__ __align__(16) short Bs[64 * 64];
    const int tid = threadIdx.x, lane = tid & 63, w = tid >> 6;
    const int g = lane >> 4, ln = lane & 15;
    const int wm = (w >> 1) * 64, wn = (w & 1) * 32;
    const int m0 = blockIdx.y * 128, n0 = blockIdx.x * 64;
    f32x4 acc[4][2] = {};
    gemm_tile(hid + (size_t)m0 * HID, HID, win + (size_t)n0 * HID, HID, HID, As, Bs, acc);
    const float inv_s = 0.07216878364870323f;
    #pragma unroll
    for (int mf = 0; mf < 4; ++mf) {
        #pragma unroll
        for (int nf = 0; nf < 2; ++nf) {
            #pragma unroll
            for (int reg = 0; reg < 4; ++reg) {
                int m = m0 + wm + mf * 16 + 4 * g + reg;
                int n = n0 + wn + nf * 16 + ln;
                int h = n / 192, c = n % 192;
                float v = acc[mf][nf][reg];
                if (c < 64)       qT[((size_t)h * SEQ + m) * DH + c]        = f2bf((v + q_bias[h * 64 + c]) * inv_s);
                else if (c < 128) kT[((size_t)h * SEQ + m) * DH + (c - 64)] = f2bf(v);
                else              vT[((size_t)h * SEQ + m) * DH + (c - 128)] = f2bf(v + v_bias[h * 64 + (c - 128)]);
            }
        }
    }
}

// ---------------- pos_k / pos_q ----------------
__global__ __launch_bounds__(256) void pos_mfma_k(
    const short* __restrict__ rel, const short* __restrict__ wpos, const short* __restrict__ wposq,
    const float* __restrict__ b_posq, short* __restrict__ posk, short* __restrict__ posq)
{
    __shared__ __align__(16) short As[128 * 64];
    __shared__ __align__(16) short Bs[64 * 64];
    const int tid = threadIdx.x, lane = tid & 63, w = tid >> 6;
    const int g = lane >> 4, ln = lane & 15;
    const int wm = (w >> 1) * 64, wn = (w & 1) * 32;
    const int m0 = blockIdx.y * 128, n0 = blockIdx.x * 64;
    const int which = blockIdx.z;
    const short* Bg = (which ? wposq : wpos) + (size_t)n0 * HID;
    f32x4 acc[4][2] = {};
    gemm_tile(rel + (size_t)m0 * HID, HID, Bg, HID, HID, As, Bs, acc);
    const float inv_s = 0.07216878364870323f;
    #pragma unroll
    for (int mf = 0; mf < 4; ++mf) {
        #pragma unroll
        for (int nf = 0; nf < 2; ++nf) {
            #pragma unroll
            for (int reg = 0; reg < 4; ++reg) {
                int s = m0 + wm + mf * 16 + 4 * g + reg;
                int o = n0 + wn + nf * 16 + ln;
                int h = o >> 6, c = o & 63;
                float v = acc[mf][nf][reg];
                if (which) posq[((size_t)h * S2 + s) * DH + c] = f2bf((v + b_posq[o]) * inv_s);
                else       posk[((size_t)h * S2 + s) * DH + c] = f2bf(v);
            }
        }
    }
}

// ---------------- band GEMMs (c2p / p2c), K=64 ----------------
__global__ __launch_bounds__(256) void band_mfma_k(
    const short* __restrict__ qT, const short* __restrict__ kT,
    const short* __restrict__ posk, const short* __restrict__ posq,
    short* __restrict__ c2p, short* __restrict__ p2c)
{
    __shared__ __align__(16) short As[128 * 64];
    __shared__ __align__(16) short Bs[64 * 64];
    const int tid = threadIdx.x, lane = tid & 63, w = tid >> 6;
    const int g = lane >> 4, ln = lane & 15;
    const int wm = (w >> 1) * 64, wn = (w & 1) * 32;
    const int m0 = blockIdx.y * 128, n0 = blockIdx.x * 64;
    const int head = blockIdx.z >> 1, which = blockIdx.z & 1;
    const short* Ag = (which ? kT : qT) + (size_t)head * SEQ * DH + (size_t)m0 * DH;
    const short* Bg = (which ? posq : posk) + (size_t)head * S2 * DH + (size_t)n0 * DH;
    short* outb = (which ? p2c : c2p) + (size_t)head * SEQ * S2;
    f32x4 acc[4][2] = {};
    gemm_tile(Ag, DH, Bg, DH, 64, As, Bs, acc);
    #pragma unroll
    for (int mf = 0; mf < 4; ++mf) {
        #pragma unroll
        for (int nf = 0; nf < 2; ++nf) {
            #pragma unroll
            for (int reg = 0; reg < 4; ++reg) {
                int m = m0 + wm + mf * 16 + 4 * g + reg;
                int n = n0 + wn + nf * 16 + ln;
                outb[(size_t)m * S2 + n] = f2bf(acc[mf][nf][reg]);
            }
        }
    }
}

// ---------------- V transpose per head: vT[h][n][d] -> vTt[h][d][n] ----------------
__global__ __launch_bounds__(256) void vtrans_k(const short* __restrict__ vT, short* __restrict__ vTt)
{
    __shared__ short T[64][72];
    const int h = blockIdx.y, n0 = blockIdx.x * 64;
    const int tid = threadIdx.x;
    const int r = tid >> 3, cb = tid & 7;
    #pragma unroll
    for (int it = 0; it < 2; ++it) {
        int row = it * 32 + r;
        *(uint4*)(&T[row][cb * 8]) = *(const uint4*)(vT + ((size_t)h * SEQ + n0 + row) * DH + cb * 8);
    }
    __syncthreads();
    #pragma unroll
    for (int it = 0; it < 2; ++it) {
        int d = it * 32 + r;
        short tmp[8];
        #pragma unroll
        for (int e = 0; e < 8; ++e) tmp[e] = T[cb * 8 + e][d];
        *(uint4*)(vTt + ((size_t)h * DH + d) * SEQ + n0 + cb * 8) = *(uint4*)tmp;
    }
}

// ---------------- MFMA flash attention: per-row bias windows, P aliased wave-private ----------------
__global__ __launch_bounds__(256) void attn_mfma_k(
    const short* __restrict__ qT, const short* __restrict__ kT, const short* __restrict__ vTt,
    const short* __restrict__ c2p, const short* __restrict__ p2c,
    const int* __restrict__ amask, const int* __restrict__ flags,
    float* __restrict__ Opart, float* __restrict__ ml)
{
    __shared__ __align__(16) char pool[34816];
    short* Ks  = (short*)pool;            // 4096 shorts (8 KB)
    short* Vs  = Ks + 4096;               // 4096 shorts (8 KB)
    short* Phw = Vs + 4096;               // 64*72 shorts (9 KB) p2c per-row windows
    short* Chw = Phw + 4608;              // 64*72 shorts (9 KB) c2p per-row windows
    const int tid = threadIdx.x, lane = tid & 63, w = tid >> 6;
    const int g = lane >> 4, ln = lane & 15;
    const int h = blockIdx.y, it = blockIdx.x, split = blockIdx.z;
    const int i0 = it * 64;
    const int iw = i0 + w * 16;
    const short* qh = qT + (size_t)h * SEQ * DH;
    const short* kh = kT + (size_t)h * SEQ * DH;
    const short* vh = vTt + (size_t)h * DH * SEQ;
    const short* ch = c2p + (size_t)h * SEQ * S2;
    const short* ph = p2c + (size_t)h * SEQ * S2;
    // P staging aliases wave-private Chw rows [16w, 16w+16): wave w's c2p bias
    // reads hit only these rows; P (16x72) is written there AFTER those reads
    // (same-wave program order) and read back only by this wave's PV.
    short* Psw = Chw + w * 1152;

    bf16x8 aq[2];
    aq[0] = *(const bf16x8*)(qh + (size_t)(iw + ln) * DH + 0  + g * 8);
    aq[1] = *(const bf16x8*)(qh + (size_t)(iw + ln) * DH + 32 + g * 8);

    f32x4 o4[4] = {};
    float mrow[4], lrow[4];
    #pragma unroll
    for (int reg = 0; reg < 4; ++reg) { mrow[reg] = -1.0e30f; lrow[reg] = 0.f; }

    const int jt0 = split * 16;
    const int fbase = it * 32 + jt0;
    // K/V staging coords (two 16B chunks per thread)
    const int r0 = tid >> 3,          cb0 = tid & 7;
    const int r1 = (256 + tid) >> 3,  cb1 = tid & 7;
    const int ksw0 = (cb0 ^ (r0 & 7)) << 3, ksw1 = (cb1 ^ (r1 & 7)) << 3;
    // window staging coords: 4 threads per row, 16-short segments
    const int wr = tid >> 2, wu = (tid & 3) * 16;

    // named prefetch registers (no arrays -> no scratch)
    uint4 kr0, kr1, vr0, vr1, cw0, cw1, pw0, pw1, cw2, pw2;

    auto issue = [&](int jt) {
        const int j0 = jt * 64;
        kr0 = *(const uint4*)(kh + (size_t)(j0 + r0) * DH + ksw0);
        vr0 = *(const uint4*)(vh + (size_t)r0 * SEQ + j0 + ksw0);
        kr1 = *(const uint4*)(kh + (size_t)(j0 + r1) * DH + ksw1);
        vr1 = *(const uint4*)(vh + (size_t)r1 * SEQ + j0 + ksw1);
        int bc = wbase(i0 + wr - j0 + 449);
        cw0 = *(const uint4*)(ch + (size_t)(i0 + wr) * S2 + bc + wu);
        cw1 = *(const uint4*)(ch + (size_t)(i0 + wr) * S2 + bc + wu + 8);
        int bp = wbase(i0 - j0 - wr + 512);
        pw0 = *(const uint4*)(ph + (size_t)(j0 + wr) * S2 + bp + wu);
        pw1 = *(const uint4*)(ph + (size_t)(j0 + wr) * S2 + bp + wu + 8);
        if (tid < 64) {
            int bc2 = wbase(i0 + tid - j0 + 449);
            cw2 = *(const uint4*)(ch + (size_t)(i0 + tid) * S2 + bc2 + 64);
            int bp2 = wbase(i0 - j0 - tid + 512);
            pw2 = *(const uint4*)(ph + (size_t)(j0 + tid) * S2 + bp2 + 64);
        }
    };
    auto commit = [&]() {
        *(uint4*)(Ks + r0 * 64 + cb0 * 8) = kr0;
        *(uint4*)(Vs + r0 * 64 + cb0 * 8) = vr0;
        *(uint4*)(Ks + r1 * 64 + cb1 * 8) = kr1;
        *(uint4*)(Vs + r1 * 64 + cb1 * 8) = vr1;
        *(uint4*)(Chw + wr * 72 + wu) = cw0;
        *(uint4*)(Chw + wr * 72 + wu + 8) = cw1;
        *(uint4*)(Phw + wr * 72 + wu) = pw0;
        *(uint4*)(Phw + wr * 72 + wu + 8) = pw1;
        if (tid < 64) {
            *(uint4*)(Chw + tid * 72 + 64) = cw2;
            *(uint4*)(Phw + tid * 72 + 64) = pw2;
        }
    };

    issue(jt0);
    int flag_cur = flags[fbase];

    for (int t = 0; t < 16; ++t) {
        const int jt = jt0 + t, j0 = jt * 64;

        __syncthreads();            // previous tile fully consumed (incl. Ps reads)
        commit();                   // drains prefetch, writes LDS
        __syncthreads();
        int flag_next = 0;
        if (t < 15) { flag_next = flags[fbase + t + 1]; issue(jt + 1); }

        if (flag_cur != 0) {
            // S = Q K^T
            f32x4 sfr[4];
            #pragma unroll
            for (int nf = 0; nf < 4; ++nf) sfr[nf] = (f32x4){0.f, 0.f, 0.f, 0.f};
            #pragma unroll
            for (int k0 = 0; k0 < 2; ++k0) {
                #pragma unroll
                for (int nf = 0; nf < 4; ++nf) {
                    int rr = nf * 16 + ln;
                    bf16x8 bk = *(const bf16x8*)(Ks + rr * 64 + (((k0 * 4 + g) ^ (rr & 7)) << 3));
                    sfr[nf] = __builtin_amdgcn_mfma_f32_16x16x32_bf16(aq[k0], bk, sfr[nf], 0, 0, 0);
                }
            }

            // per-row window base pointers (this tile)
            const short* Crow_[4];
            #pragma unroll
            for (int reg = 0; reg < 4; ++reg) {
                int il = w * 16 + 4 * g + reg;
                Crow_[reg] = Chw + il * 72 - wbase(i0 + il - j0 + 449);
            }

            // bias from LDS windows (+ mask only on mixed tiles)
            float p[4][4];
            #pragma unroll
            for (int nf = 0; nf < 4; ++nf) {
                int jr = nf * 16 + ln;
                const short* Prow = Phw + jr * 72 - wbase(i0 - j0 - jr + 512);
                #pragma unroll
                for (int reg = 0; reg < 4; ++reg) {
                    int i = iw + 4 * g + reg;
                    int s = i - (j0 + jr) + 512; s = s < 0 ? 0 : (s > 1023 ? 1023 : s);
                    float sc = sfr[nf][reg] + bf2f(Crow_[reg][s]) + bf2f(Prow[s]);
                    if (flag_cur != 2)
                        sc = amask[(size_t)i * SEQ + (j0 + jr)] ? sc : -1.0e30f;
                    p[reg][nf] = sc;
                }
            }

            // online softmax per row
            float scl[4];
            #pragma unroll
            for (int reg = 0; reg < 4; ++reg) {
                float mx = fmaxf(fmaxf(p[reg][0], p[reg][1]), fmaxf(p[reg][2], p[reg][3]));
                #pragma unroll
                for (int off = 1; off < 16; off <<= 1) mx = fmaxf(mx, __shfl_xor(mx, off, 64));
                float nm = fmaxf(mrow[reg], mx);
                bool live = nm > -5.0e29f;
                float sc = live ? __expf(mrow[reg] - nm) : 1.f;
                float rs = 0.f;
                #pragma unroll
                for (int nf = 0; nf < 4; ++nf) {
                    float e = live ? __expf(p[reg][nf] - nm) : 0.f;
                    p[reg][nf] = e; rs += e;
                }
                #pragma unroll
                for (int off = 1; off < 16; off <<= 1) rs += __shfl_xor(rs, off, 64);
                lrow[reg] = lrow[reg] * sc + rs;
                mrow[reg] = nm;
                scl[reg] = sc;
            }

            // write P into wave-private aliased region (after all c2p reads)
            #pragma unroll
            for (int reg = 0; reg < 4; ++reg)
                #pragma unroll
                for (int nf = 0; nf < 4; ++nf)
                    Psw[(4 * g + reg) * 72 + nf * 16 + ln] = f2bf(p[reg][nf]);

            // rescale O^T (lane owns col i = ln) with redistributed scale
            {
                int srcl = ((ln >> 2) << 4) + ln;
                float s0 = __shfl(scl[0], srcl, 64), s1 = __shfl(scl[1], srcl, 64);
                float s2 = __shfl(scl[2], srcl, 64), s3 = __shfl(scl[3], srcl, 64);
                int rsel = ln & 3;
                float sc = rsel == 0 ? s0 : (rsel == 1 ? s1 : (rsel == 2 ? s2 : s3));
                #pragma unroll
                for (int mf = 0; mf < 4; ++mf)
                    #pragma unroll
                    for (int reg = 0; reg < 4; ++reg) o4[mf][reg] *= sc;
            }

            // O^T += V^T * P^T
            #pragma unroll
            for (int k0 = 0; k0 < 2; ++k0) {
                bf16x8 bp = *(const bf16x8*)(Psw + ln * 72 + k0 * 32 + g * 8);
                #pragma unroll
                for (int mf = 0; mf < 4; ++mf) {
                    int rr = mf * 16 + ln;
                    bf16x8 av = *(const bf16x8*)(Vs + rr * 64 + (((k0 * 4 + g) ^ (rr & 7)) << 3));
                    o4[mf] = __builtin_amdgcn_mfma_f32_16x16x32_bf16(av, bp, o4[mf], 0, 0, 0);
                }
            }
        }
        flag_cur = flag_next;
    }

    // ---- store partials: m/l per row, O numerator via LDS transpose ----
    if (ln == 0) {
        #pragma unroll
        for (int reg = 0; reg < 4; ++reg) {
            int i = iw + 4 * g + reg;
            int row = (split * 16 + h) * SEQ + i;
            ml[row] = mrow[reg];
            ml[65536 + row] = lrow[reg];
        }
    }
    __syncthreads();
    float* Tf = (float*)pool;   // 64 x 68 f32 = 17408 B (fits pool)
    #pragma unroll
    for (int mf = 0; mf < 4; ++mf)
        #pragma unroll
        for (int reg = 0; reg < 4; ++reg)
            Tf[(w * 16 + ln) * 68 + mf * 16 + 4 * g + reg] = o4[mf][reg];
    __syncthreads();
    {
        const int r = tid >> 2, sgm = (tid & 3) << 4;
        const int row = (split * 16 + h) * SEQ + i0 + r;
        float* dst = Opart + (size_t)row * 64 + sgm;
        #pragma unroll
        for (int k = 0; k < 4; ++k)
            ((float4*)dst)[k] = *(float4*)(Tf + r * 68 + sgm + k * 4);
    }
}

// ---------------- combine the two j-splits ----------------
__global__ __launch_bounds__(256) void combine_k(const float* __restrict__ Opart,
                                                 const float* __restrict__ ml,
                                                 float* __restrict__ out)
{
    const int h = blockIdx.y, i0 = blockIdx.x * 64;
    const int tid = threadIdx.x;
    const int r = tid >> 2, sgm = (tid & 3) << 4;
    const int i = i0 + r;
    const int row0 = h * SEQ + i;
    const int row1 = 16 * SEQ + row0;
    float m1 = ml[row0], m2 = ml[row1];
    float l1 = ml[65536 + row0], l2 = ml[65536 + row1];
    float M = fmaxf(m1, m2);
    float w1 = __expf(m1 - M), w2 = __expf(m2 - M);
    float denom = l1 * w1 + l2 * w2;
    float rd = denom > 0.f ? 1.f / denom : 0.f;
    const float4* o1p = (const float4*)(Opart + (size_t)row0 * 64 + sgm);
    const float4* o2p = (const float4*)(Opart + (size_t)row1 * 64 + sgm);
    float4* op = (float4*)(out + (size_t)i * HID + h * 64 + sgm);
    #pragma unroll
    for (int k = 0; k < 4; ++k) {
        float4 a = o1p[k], b = o2p[k], o;
        o.x = (a.x * w1 + b.x * w2) * rd;
        o.y = (a.y * w1 + b.y * w2) * rd;
        o.z = (a.z * w1 + b.z * w2) * rd;
        o.w = (a.w * w1 + b.w * w2) * rd;
        op[k] = o;
    }
}

extern "C" void kernel_launch(void* const* d_in, const int* in_sizes, int n_in,
                              void* d_out, int out_size, void* d_ws, size_t ws_size,
                              hipStream_t stream)
{
    const float* hidden  = (const float*)d_in[0];
    const int*   amask   = (const int*)  d_in[1];
    const float* W_in    = (const float*)d_in[2];
    const float* q_bias  = (const float*)d_in[3];
    const float* v_bias  = (const float*)d_in[4];
    const float* W_pos   = (const float*)d_in[5];
    const float* W_posq  = (const float*)d_in[6];
    const float* b_posq  = (const float*)d_in[7];
    const float* rel_emb = (const float*)d_in[8];
    float* out = (float*)d_out;

    short* ws = (short*)d_ws;
    // persistent (live into attn):
    short* qT   = ws;                    // 2,097,152
    short* kT   = ws + 2097152;          // 2,097,152
    short* vTt  = ws + 4194304;          // 2,097,152
    short* c2p  = ws + 6291456;          // 33,554,432
    short* p2c  = ws + 39845888;         // 33,554,432
    // scratch region (staged aliases):
    short* scr      = ws + 73400320;
    short* hid_bf   = scr;               // 2,097,152   (phase 1)
    short* win_bf   = scr + 2097152;     // 3,145,728   (phase 1)
    short* vT       = scr + 5242880;     // 2,097,152   (phase 1-2)
    short* rel_bf   = scr;               // 1,048,576   (phase 2, after qkv)
    short* wpos_bf  = scr + 1048576;     // 1,048,576   (phase 2)
    short* wposq_bf = scr + 2097152;     // 1,048,576   (phase 2)
    short* posk     = scr + 3145728;     // 1,048,576   (phase 2-3)
    short* posq     = scr + 4194304;     // 1,048,576   (phase 2-3)
    // attn-phase aliases (after band/vtrans):
    float* Opart = (float*)scr;                      // 4,194,304 floats
    float* ml    = (float*)(scr + 8388608);          // 131,072 floats
    int*   flags = (int*)(scr + 8650752);            // 1,024 ints (beyond prologue extent)

    cvt_bf16_k<<<1024, 256, 0, stream>>>(hidden, hid_bf, 262144);
    cvt_bf16_k<<<1536, 256, 0, stream>>>(W_in, win_bf, 393216);
    maskflag_k<<<dim3(32, 32), 256, 0, stream>>>(amask, flags);
    qkv_mfma_k<<<dim3(48, 16), 256, 0, stream>>>(hid_bf, win_bf, q_bias, v_bias, qT, kT, vT);
    cvt3_bf16_k<<<1536, 256, 0, stream>>>(rel_emb, W_pos, W_posq, rel_bf, wpos_bf, wposq_bf);
    pos_mfma_k<<<dim3(16, 8, 2), 256, 0, stream>>>(rel_bf, wpos_bf, wposq_bf, b_posq, posk, posq);
    vtrans_k<<<dim3(32, 16), 256, 0, stream>>>(vT, vTt);
    band_mfma_k<<<dim3(16, 16, 32), 256, 0, stream>>>(qT, kT, posk, posq, c2p, p2c);
    attn_mfma_k<<<dim3(32, 16, 2), 256, 0, stream>>>(qT, kT, vTt, c2p, p2c, amask, flags, Opart, ml);
    combine_k<<<dim3(32, 16), 256, 0, stream>>>(Opart, ml, out);
}

// Round 9
// 213.241 us; speedup vs baseline: 1.0820x; 1.0820x over previous
//
#include <hip/hip_runtime.h>

#define SEQ   2048
#define HID   1024
#define NHEAD 16
#define DH    64
#define S2    1024

typedef short bf16x8 __attribute__((ext_vector_type(8)));
typedef float f32x4  __attribute__((ext_vector_type(4)));

static __device__ __forceinline__ short f2bf(float f) {
    unsigned u = __float_as_uint(f);
    unsigned r = (u + 0x7fffu + ((u >> 16) & 1u)) >> 16;
    return (short)r;
}
static __device__ __forceinline__ float bf2f(short h) {
    return __uint_as_float(((unsigned)(unsigned short)h) << 16);
}
// window base: 8-aligned, covers clip([a, a+63]) within [base, base+71]
static __device__ __forceinline__ int wbase(int a) {
    int b = a < 0 ? 0 : (a > 952 ? 952 : a);
    return b & ~7;
}

// ---------------- fp32 -> bf16 conversion ----------------
__global__ __launch_bounds__(256) void cvt_bf16_k(const float* __restrict__ in,
                                                  short* __restrict__ out, int n8) {
    int idx = blockIdx.x * 256 + threadIdx.x;
    if (idx < n8) {
        const float4 a = ((const float4*)in)[idx * 2];
        const float4 b = ((const float4*)in)[idx * 2 + 1];
        bf16x8 r;
        r[0] = f2bf(a.x); r[1] = f2bf(a.y); r[2] = f2bf(a.z); r[3] = f2bf(a.w);
        r[4] = f2bf(b.x); r[5] = f2bf(b.y); r[6] = f2bf(b.z); r[7] = f2bf(b.w);
        ((bf16x8*)out)[idx] = r;
    }
}

// three equal-size 1M-element converts in one launch (rel, W_pos, W_posq)
__global__ __launch_bounds__(256) void cvt3_bf16_k(
    const float* __restrict__ in0, const float* __restrict__ in1, const float* __restrict__ in2,
    short* __restrict__ out0, short* __restrict__ out1, short* __restrict__ out2) {
    int b = blockIdx.x, sel = b >> 9;
    int idx = (b & 511) * 256 + threadIdx.x;
    const float* in = sel == 0 ? in0 : (sel == 1 ? in1 : in2);
    short* out = sel == 0 ? out0 : (sel == 1 ? out1 : out2);
    const float4 a = ((const float4*)in)[idx * 2];
    const float4 b4 = ((const float4*)in)[idx * 2 + 1];
    bf16x8 r;
    r[0] = f2bf(a.x); r[1] = f2bf(a.y); r[2] = f2bf(a.z); r[3] = f2bf(a.w);
    r[4] = f2bf(b4.x); r[5] = f2bf(b4.y); r[6] = f2bf(b4.z); r[7] = f2bf(b4.w);
    ((bf16x8*)out)[idx] = r;
}

// ---------------- mask tile flags: 0 all-zero, 1 mixed, 2 all-ones ----------------
__global__ __launch_bounds__(256) void maskflag_k(const int* __restrict__ amask, int* __restrict__ flags)
{
    __shared__ int sall[4], sany[4];
    const int jt = blockIdx.x, it = blockIdx.y;
    const int tid = threadIdx.x;
    const int r = tid >> 2, cseg = (tid & 3) << 4;
    const int4* rp = (const int4*)(amask + (size_t)(it * 64 + r) * SEQ + jt * 64 + cseg);
    int allnz = 1, anynz = 0;
    #pragma unroll
    for (int e = 0; e < 4; ++e) {
        int4 v = rp[e];
        allnz &= (v.x != 0) & (v.y != 0) & (v.z != 0) & (v.w != 0);
        anynz |= (v.x != 0) | (v.y != 0) | (v.z != 0) | (v.w != 0);
    }
    unsigned long long ba = __ballot(allnz != 0);
    unsigned long long bo = __ballot(anynz != 0);
    const int w = tid >> 6;
    if ((tid & 63) == 0) { sall[w] = (ba == ~0ull); sany[w] = (bo != 0ull); }
    __syncthreads();
    if (tid == 0) {
        int all4 = sall[0] & sall[1] & sall[2] & sall[3];
        int any4 = sany[0] | sany[1] | sany[2] | sany[3];
        flags[it * 32 + jt] = all4 ? 2 : (any4 ? 1 : 0);
    }
}

// ---------------- shared MFMA GEMM core: C[128x64] += A[128xK] * B[64xK]^T ----------------
static __device__ __forceinline__ void gemm_tile(
    const short* __restrict__ Ag, int lda,
    const short* __restrict__ Bg, int ldb,
    int K, short* As, short* Bs, f32x4 (&acc)[4][2])
{
    const int tid = threadIdx.x;
    const int lane = tid & 63, w = tid >> 6;
    const int g = lane >> 4, ln = lane & 15;
    const int wm = (w >> 1) * 64, wn = (w & 1) * 32;
    for (int kt = 0; kt < K; kt += 64) {
        __syncthreads();
        #pragma unroll
        for (int it = 0; it < 4; ++it) {
            int c = it * 256 + tid;
            int r = c >> 3, cb = c & 7;
            uint4 v = *(const uint4*)(Ag + (size_t)r * lda + kt + ((cb ^ (r & 7)) << 3));
            *(uint4*)(As + r * 64 + cb * 8) = v;
        }
        #pragma unroll
        for (int it = 0; it < 2; ++it) {
            int c = it * 256 + tid;
            int r = c >> 3, cb = c & 7;
            uint4 v = *(const uint4*)(Bg + (size_t)r * ldb + kt + ((cb ^ (r & 7)) << 3));
            *(uint4*)(Bs + r * 64 + cb * 8) = v;
        }
        __syncthreads();
        #pragma unroll
        for (int k0 = 0; k0 < 2; ++k0) {
            bf16x8 bfr[2];
            #pragma unroll
            for (int nf = 0; nf < 2; ++nf) {
                int rr = wn + nf * 16 + ln;
                int kc = (k0 * 4 + g) ^ (rr & 7);
                bfr[nf] = *(const bf16x8*)(Bs + rr * 64 + kc * 8);
            }
            #pragma unroll
            for (int mf = 0; mf < 4; ++mf) {
                int rr = wm + mf * 16 + ln;
                int kc = (k0 * 4 + g) ^ (rr & 7);
                bf16x8 afr = *(const bf16x8*)(As + rr * 64 + kc * 8);
                #pragma unroll
                for (int nf = 0; nf < 2; ++nf)
                    acc[mf][nf] = __builtin_amdgcn_mfma_f32_16x16x32_bf16(afr, bfr[nf], acc[mf][nf], 0, 0, 0);
            }
        }
    }
}

// ---------------- QKV projection ----------------
__global__ __launch_bounds__(256) void qkv_mfma_k(
    const short* __restrict__ hid, const short* __restrict__ win,
    const float* __restrict__ q_bias, const float* __restrict__ v_bias,
    short* __restrict__ qT, short* __restrict__ kT, short* __restrict__ vT)
{
    __shared__ __align__(16) short As[128 * 64];
    __shared__ __align__(16) short Bs[64 * 64];
    const int tid = threadIdx.x, lane = tid & 63, w = tid >> 6;
    const int g = lane >> 4, ln = lane & 15;
    const int wm = (w >> 1) * 64, wn = (w & 1) * 32;
    const int m0 = blockIdx.y * 128, n0 = blockIdx.x * 64;
    f32x4 acc[4][2] = {};
    gemm_tile(hid + (size_t)m0 * HID, HID, win + (size_t)n0 * HID, HID, HID, As, Bs, acc);
    const float inv_s = 0.07216878364870323f;
    #pragma unroll
    for (int mf = 0; mf < 4; ++mf) {
        #pragma unroll
        for (int nf = 0; nf < 2; ++nf) {
            #pragma unroll
            for (int reg = 0; reg < 4; ++reg) {
                int m = m0 + wm + mf * 16 + 4 * g + reg;
                int n = n0 + wn + nf * 16 + ln;
                int h = n / 192, c = n % 192;
                float v = acc[mf][nf][reg];
                if (c < 64)       qT[((size_t)h * SEQ + m) * DH + c]        = f2bf((v + q_bias[h * 64 + c]) * inv_s);
                else if (c < 128) kT[((size_t)h * SEQ + m) * DH + (c - 64)] = f2bf(v);
                else              vT[((size_t)h * SEQ + m) * DH + (c - 128)] = f2bf(v + v_bias[h * 64 + (c - 128)]);
            }
        }
    }
}

// ---------------- pos_k / pos_q ----------------
__global__ __launch_bounds__(256) void pos_mfma_k(
    const short* __restrict__ rel, const short* __restrict__ wpos, const short* __restrict__ wposq,
    const float* __restrict__ b_posq, short* __restrict__ posk, short* __restrict__ posq)
{
    __shared__ __align__(16) short As[128 * 64];
    __shared__ __align__(16) short Bs[64 * 64];
    const int tid = threadIdx.x, lane = tid & 63, w = tid >> 6;
    const int g = lane >> 4, ln = lane & 15;
    const int wm = (w >> 1) * 64, wn = (w & 1) * 32;
    const int m0 = blockIdx.y * 128, n0 = blockIdx.x * 64;
    const int which = blockIdx.z;
    const short* Bg = (which ? wposq : wpos) + (size_t)n0 * HID;
    f32x4 acc[4][2] = {};
    gemm_tile(rel + (size_t)m0 * HID, HID, Bg, HID, HID, As, Bs, acc);
    const float inv_s = 0.07216878364870323f;
    #pragma unroll
    for (int mf = 0; mf < 4; ++mf) {
        #pragma unroll
        for (int nf = 0; nf < 2; ++nf) {
            #pragma unroll
            for (int reg = 0; reg < 4; ++reg) {
                int s = m0 + wm + mf * 16 + 4 * g + reg;
                int o = n0 + wn + nf * 16 + ln;
                int h = o >> 6, c = o & 63;
                float v = acc[mf][nf][reg];
                if (which) posq[((size_t)h * S2 + s) * DH + c] = f2bf((v + b_posq[o]) * inv_s);
                else       posk[((size_t)h * S2 + s) * DH + c] = f2bf(v);
            }
        }
    }
}

// ---------------- band GEMMs (c2p / p2c), K=64 ----------------
__global__ __launch_bounds__(256) void band_mfma_k(
    const short* __restrict__ qT, const short* __restrict__ kT,
    const short* __restrict__ posk, const short* __restrict__ posq,
    short* __restrict__ c2p, short* __restrict__ p2c)
{
    __shared__ __align__(16) short As[128 * 64];
    __shared__ __align__(16) short Bs[64 * 64];
    const int tid = threadIdx.x, lane = tid & 63, w = tid >> 6;
    const int g = lane >> 4, ln = lane & 15;
    const int wm = (w >> 1) * 64, wn = (w & 1) * 32;
    const int m0 = blockIdx.y * 128, n0 = blockIdx.x * 64;
    const int head = blockIdx.z >> 1, which = blockIdx.z & 1;
    const short* Ag = (which ? kT : qT) + (size_t)head * SEQ * DH + (size_t)m0 * DH;
    const short* Bg = (which ? posq : posk) + (size_t)head * S2 * DH + (size_t)n0 * DH;
    short* outb = (which ? p2c : c2p) + (size_t)head * SEQ * S2;
    f32x4 acc[4][2] = {};
    gemm_tile(Ag, DH, Bg, DH, 64, As, Bs, acc);
    #pragma unroll
    for (int mf = 0; mf < 4; ++mf) {
        #pragma unroll
        for (int nf = 0; nf < 2; ++nf) {
            #pragma unroll
            for (int reg = 0; reg < 4; ++reg) {
                int m = m0 + wm + mf * 16 + 4 * g + reg;
                int n = n0 + wn + nf * 16 + ln;
                outb[(size_t)m * S2 + n] = f2bf(acc[mf][nf][reg]);
            }
        }
    }
}

// ---------------- V transpose per head: vT[h][n][d] -> vTt[h][d][n] ----------------
__global__ __launch_bounds__(256) void vtrans_k(const short* __restrict__ vT, short* __restrict__ vTt)
{
    __shared__ short T[64][72];
    const int h = blockIdx.y, n0 = blockIdx.x * 64;
    const int tid = threadIdx.x;
    const int r = tid >> 3, cb = tid & 7;
    #pragma unroll
    for (int it = 0; it < 2; ++it) {
        int row = it * 32 + r;
        *(uint4*)(&T[row][cb * 8]) = *(const uint4*)(vT + ((size_t)h * SEQ + n0 + row) * DH + cb * 8);
    }
    __syncthreads();
    #pragma unroll
    for (int it = 0; it < 2; ++it) {
        int d = it * 32 + r;
        short tmp[8];
        #pragma unroll
        for (int e = 0; e < 8; ++e) tmp[e] = T[cb * 8 + e][d];
        *(uint4*)(vTt + ((size_t)h * DH + d) * SEQ + n0 + cb * 8) = *(uint4*)tmp;
    }
}

// ---------------- MFMA flash attention: swapped QK^T (row i lane-local) ----------------
__global__ __launch_bounds__(256) void attn_mfma_k(
    const short* __restrict__ qT, const short* __restrict__ kT, const short* __restrict__ vTt,
    const short* __restrict__ c2p, const short* __restrict__ p2c,
    const int* __restrict__ amask, const int* __restrict__ flags,
    float* __restrict__ Opart, float* __restrict__ ml)
{
    __shared__ __align__(16) char pool[34816];
    short* Ks  = (short*)pool;            // 4096 shorts (8 KB)
    short* Vs  = Ks + 4096;               // 4096 shorts (8 KB)
    short* Phw = Vs + 4096;               // 64*72 shorts (9 KB) p2c per-row windows
    short* Chw = Phw + 4608;              // 64*72 shorts (9 KB) c2p per-row windows
    const int tid = threadIdx.x, lane = tid & 63, w = tid >> 6;
    const int g = lane >> 4, ln = lane & 15;
    const int h = blockIdx.y, it = blockIdx.x, split = blockIdx.z;
    const int i0 = it * 64;
    const int iw = i0 + w * 16;
    const short* qh = qT + (size_t)h * SEQ * DH;
    const short* kh = kT + (size_t)h * SEQ * DH;
    const short* vh = vTt + (size_t)h * DH * SEQ;
    const short* ch = c2p + (size_t)h * SEQ * S2;
    const short* ph = p2c + (size_t)h * SEQ * S2;
    // P staging aliases wave-private Chw rows [16w, 16w+16): wave w's c2p bias
    // reads hit only these rows (il = w*16 + ln); P is written there AFTER those
    // reads (same-wave program order) and read back only by this wave's PV.
    short* Psw = Chw + w * 1152;

    bf16x8 aq[2];
    aq[0] = *(const bf16x8*)(qh + (size_t)(iw + ln) * DH + 0  + g * 8);
    aq[1] = *(const bf16x8*)(qh + (size_t)(iw + ln) * DH + 32 + g * 8);

    f32x4 o4[4] = {};
    // lane-local row stats: this lane owns row i = iw + ln (replicated across g)
    float mrow = -1.0e30f, lrow = 0.f;

    const int jt0 = split * 16;
    const int fbase = it * 32 + jt0;
    // K/V staging coords (two 16B chunks per thread)
    const int r0 = tid >> 3,          cb0 = tid & 7;
    const int r1 = (256 + tid) >> 3,  cb1 = tid & 7;
    const int ksw0 = (cb0 ^ (r0 & 7)) << 3, ksw1 = (cb1 ^ (r1 & 7)) << 3;
    // window staging coords: 4 threads per row, 16-short segments
    const int wr = tid >> 2, wu = (tid & 3) * 16;

    // named prefetch registers (no arrays -> no scratch)
    uint4 kr0, kr1, vr0, vr1, cw0, cw1, pw0, pw1, cw2, pw2;

    auto issue = [&](int jt) {
        const int j0 = jt * 64;
        kr0 = *(const uint4*)(kh + (size_t)(j0 + r0) * DH + ksw0);
        vr0 = *(const uint4*)(vh + (size_t)r0 * SEQ + j0 + ksw0);
        kr1 = *(const uint4*)(kh + (size_t)(j0 + r1) * DH + ksw1);
        vr1 = *(const uint4*)(vh + (size_t)r1 * SEQ + j0 + ksw1);
        int bc = wbase(i0 + wr - j0 + 449);
        cw0 = *(const uint4*)(ch + (size_t)(i0 + wr) * S2 + bc + wu);
        cw1 = *(const uint4*)(ch + (size_t)(i0 + wr) * S2 + bc + wu + 8);
        int bp = wbase(i0 - j0 - wr + 512);
        pw0 = *(const uint4*)(ph + (size_t)(j0 + wr) * S2 + bp + wu);
        pw1 = *(const uint4*)(ph + (size_t)(j0 + wr) * S2 + bp + wu + 8);
        if (tid < 64) {
            int bc2 = wbase(i0 + tid - j0 + 449);
            cw2 = *(const uint4*)(ch + (size_t)(i0 + tid) * S2 + bc2 + 64);
            int bp2 = wbase(i0 - j0 - tid + 512);
            pw2 = *(const uint4*)(ph + (size_t)(j0 + tid) * S2 + bp2 + 64);
        }
    };
    auto commit = [&]() {
        *(uint4*)(Ks + r0 * 64 + cb0 * 8) = kr0;
        *(uint4*)(Vs + r0 * 64 + cb0 * 8) = vr0;
        *(uint4*)(Ks + r1 * 64 + cb1 * 8) = kr1;
        *(uint4*)(Vs + r1 * 64 + cb1 * 8) = vr1;
        *(uint4*)(Chw + wr * 72 + wu) = cw0;
        *(uint4*)(Chw + wr * 72 + wu + 8) = cw1;
        *(uint4*)(Phw + wr * 72 + wu) = pw0;
        *(uint4*)(Phw + wr * 72 + wu + 8) = pw1;
        if (tid < 64) {
            *(uint4*)(Chw + tid * 72 + 64) = cw2;
            *(uint4*)(Phw + tid * 72 + 64) = pw2;
        }
    };

    issue(jt0);
    int flag_cur = flags[fbase];

    const int il = w * 16 + ln;     // i-local (this lane's row)
    const int i  = i0 + il;

    for (int t = 0; t < 16; ++t) {
        const int jt = jt0 + t, j0 = jt * 64;

        __syncthreads();            // previous tile fully consumed (incl. Ps reads)
        commit();                   // drains prefetch, writes LDS
        __syncthreads();
        int flag_next = 0;
        if (t < 15) { flag_next = flags[fbase + t + 1]; issue(jt + 1); }

        if (flag_cur != 0) {
            // S^T = K Q^T via mfma(A=K, B=Q): D col=ln -> i-local, row=4g+reg -> j-local
            f32x4 sfr[4];
            #pragma unroll
            for (int nf = 0; nf < 4; ++nf) sfr[nf] = (f32x4){0.f, 0.f, 0.f, 0.f};
            #pragma unroll
            for (int k0 = 0; k0 < 2; ++k0) {
                #pragma unroll
                for (int nf = 0; nf < 4; ++nf) {
                    int rr = nf * 16 + ln;
                    bf16x8 ak = *(const bf16x8*)(Ks + rr * 64 + (((k0 * 4 + g) ^ (rr & 7)) << 3));
                    sfr[nf] = __builtin_amdgcn_mfma_f32_16x16x32_bf16(ak, aq[k0], sfr[nf], 0, 0, 0);
                }
            }

            // bias: lane-local c2p row pointer; p2c per-element window read
            const short* Crow = Chw + il * 72 - wbase(i - j0 + 449);
            const int Cc = i0 - j0 + 512;
            float p[4][4];
            #pragma unroll
            for (int nf = 0; nf < 4; ++nf) {
                #pragma unroll
                for (int reg = 0; reg < 4; ++reg) {
                    int jr = 16 * nf + 4 * g + reg;
                    int s = i - (j0 + jr) + 512; s = s < 0 ? 0 : (s > 1023 ? 1023 : s);
                    int wbp = Cc - jr; wbp = wbp < 0 ? 0 : (wbp > 952 ? 952 : wbp); wbp &= ~7;
                    float sc = sfr[nf][reg] + bf2f(Crow[s]) + bf2f(Phw[jr * 72 + (s - wbp)]);
                    if (flag_cur != 2)
                        sc = amask[(size_t)i * SEQ + (j0 + jr)] ? sc : -1.0e30f;
                    p[nf][reg] = sc;
                }
            }

            // online softmax: row i is lane-local (16 values) + 2 cross-g shuffles
            float mx = p[0][0];
            #pragma unroll
            for (int nf = 0; nf < 4; ++nf)
                #pragma unroll
                for (int reg = 0; reg < 4; ++reg) mx = fmaxf(mx, p[nf][reg]);
            mx = fmaxf(mx, __shfl_xor(mx, 16, 64));
            mx = fmaxf(mx, __shfl_xor(mx, 32, 64));
            float nm = fmaxf(mrow, mx);
            bool live = nm > -5.0e29f;
            float sc = live ? __expf(mrow - nm) : 1.f;
            float rs = 0.f;
            #pragma unroll
            for (int nf = 0; nf < 4; ++nf)
                #pragma unroll
                for (int reg = 0; reg < 4; ++reg) {
                    float e = live ? __expf(p[nf][reg] - nm) : 0.f;
                    p[nf][reg] = e; rs += e;
                }
            rs += __shfl_xor(rs, 16, 64);
            rs += __shfl_xor(rs, 32, 64);
            lrow = lrow * sc + rs;
            mrow = nm;

            // write P into wave-private aliased region (after all c2p reads):
            // row = i-local = ln, col = j-local
            #pragma unroll
            for (int nf = 0; nf < 4; ++nf)
                #pragma unroll
                for (int reg = 0; reg < 4; ++reg)
                    Psw[ln * 72 + 16 * nf + 4 * g + reg] = f2bf(p[nf][reg]);

            // rescale O^T: lane owns col i = ln -> lane-local scale, no shuffles
            #pragma unroll
            for (int mf = 0; mf < 4; ++mf)
                #pragma unroll
                for (int reg = 0; reg < 4; ++reg) o4[mf][reg] *= sc;

            // O^T += V^T * P^T  (B-frag row n = ln = i-local, k = j)
            #pragma unroll
            for (int k0 = 0; k0 < 2; ++k0) {
                bf16x8 bp = *(const bf16x8*)(Psw + ln * 72 + k0 * 32 + g * 8);
                #pragma unroll
                for (int mf = 0; mf < 4; ++mf) {
                    int rr = mf * 16 + ln;
                    bf16x8 av = *(const bf16x8*)(Vs + rr * 64 + (((k0 * 4 + g) ^ (rr & 7)) << 3));
                    o4[mf] = __builtin_amdgcn_mfma_f32_16x16x32_bf16(av, bp, o4[mf], 0, 0, 0);
                }
            }
        }
        flag_cur = flag_next;
    }

    // ---- store partials: m/l per row (lane-local, g==0 lanes), O via LDS transpose ----
    if (lane < 16) {
        int row = (split * 16 + h) * SEQ + (iw + ln);
        ml[row] = mrow;
        ml[65536 + row] = lrow;
    }
    __syncthreads();
    float* Tf = (float*)pool;   // 64 x 68 f32 = 17408 B (fits pool)
    #pragma unroll
    for (int mf = 0; mf < 4; ++mf)
        #pragma unroll
        for (int reg = 0; reg < 4; ++reg)
            Tf[(w * 16 + ln) * 68 + mf * 16 + 4 * g + reg] = o4[mf][reg];
    __syncthreads();
    {
        const int r = tid >> 2, sgm = (tid & 3) << 4;
        const int row = (split * 16 + h) * SEQ + i0 + r;
        float* dst = Opart + (size_t)row * 64 + sgm;
        #pragma unroll
        for (int k = 0; k < 4; ++k)
            ((float4*)dst)[k] = *(float4*)(Tf + r * 68 + sgm + k * 4);
    }
}

// ---------------- combine the two j-splits ----------------
__global__ __launch_bounds__(256) void combine_k(const float* __restrict__ Opart,
                                                 const float* __restrict__ ml,
                                                 float* __restrict__ out)
{
    const int h = blockIdx.y, i0 = blockIdx.x * 64;
    const int tid = threadIdx.x;
    const int r = tid >> 2, sgm = (tid & 3) << 4;
    const int i = i0 + r;
    const int row0 = h * SEQ + i;
    const int row1 = 16 * SEQ + row0;
    float m1 = ml[row0], m2 = ml[row1];
    float l1 = ml[65536 + row0], l2 = ml[65536 + row1];
    float M = fmaxf(m1, m2);
    float w1 = __expf(m1 - M), w2 = __expf(m2 - M);
    float denom = l1 * w1 + l2 * w2;
    float rd = denom > 0.f ? 1.f / denom : 0.f;
    const float4* o1p = (const float4*)(Opart + (size_t)row0 * 64 + sgm);
    const float4* o2p = (const float4*)(Opart + (size_t)row1 * 64 + sgm);
    float4* op = (float4*)(out + (size_t)i * HID + h * 64 + sgm);
    #pragma unroll
    for (int k = 0; k < 4; ++k) {
        float4 a = o1p[k], b = o2p[k], o;
        o.x = (a.x * w1 + b.x * w2) * rd;
        o.y = (a.y * w1 + b.y * w2) * rd;
        o.z = (a.z * w1 + b.z * w2) * rd;
        o.w = (a.w * w1 + b.w * w2) * rd;
        op[k] = o;
    }
}

extern "C" void kernel_launch(void* const* d_in, const int* in_sizes, int n_in,
                              void* d_out, int out_size, void* d_ws, size_t ws_size,
                              hipStream_t stream)
{
    const float* hidden  = (const float*)d_in[0];
    const int*   amask   = (const int*)  d_in[1];
    const float* W_in    = (const float*)d_in[2];
    const float* q_bias  = (const float*)d_in[3];
    const float* v_bias  = (const float*)d_in[4];
    const float* W_pos   = (const float*)d_in[5];
    const float* W_posq  = (const float*)d_in[6];
    const float* b_posq  = (const float*)d_in[7];
    const float* rel_emb = (const float*)d_in[8];
    float* out = (float*)d_out;

    short* ws = (short*)d_ws;
    // persistent (live into attn):
    short* qT   = ws;                    // 2,097,152
    short* kT   = ws + 2097152;          // 2,097,152
    short* vTt  = ws + 4194304;          // 2,097,152
    short* c2p  = ws + 6291456;          // 33,554,432
    short* p2c  = ws + 39845888;         // 33,554,432
    // scratch region (staged aliases):
    short* scr      = ws + 73400320;
    short* hid_bf   = scr;               // 2,097,152   (phase 1)
    short* win_bf   = scr + 2097152;     // 3,145,728   (phase 1)
    short* vT       = scr + 5242880;     // 2,097,152   (phase 1-2)
    short* rel_bf   = scr;               // 1,048,576   (phase 2, after qkv)
    short* wpos_bf  = scr + 1048576;     // 1,048,576   (phase 2)
    short* wposq_bf = scr + 2097152;     // 1,048,576   (phase 2)
    short* posk     = scr + 3145728;     // 1,048,576   (phase 2-3)
    short* posq     = scr + 4194304;     // 1,048,576   (phase 2-3)
    // attn-phase aliases (after band/vtrans):
    float* Opart = (float*)scr;                      // 4,194,304 floats
    float* ml    = (float*)(scr + 8388608);          // 131,072 floats
    int*   flags = (int*)(scr + 8650752);            // 1,024 ints (beyond prologue extent)

    cvt_bf16_k<<<1024, 256, 0, stream>>>(hidden, hid_bf, 262144);
    cvt_bf16_k<<<1536, 256, 0, stream>>>(W_in, win_bf, 393216);
    maskflag_k<<<dim3(32, 32), 256, 0, stream>>>(amask, flags);
    qkv_mfma_k<<<dim3(48, 16), 256, 0, stream>>>(hid_bf, win_bf, q_bias, v_bias, qT, kT, vT);
    cvt3_bf16_k<<<1536, 256, 0, stream>>>(rel_emb, W_pos, W_posq, rel_bf, wpos_bf, wposq_bf);
    pos_mfma_k<<<dim3(16, 8, 2), 256, 0, stream>>>(rel_bf, wpos_bf, wposq_bf, b_posq, posk, posq);
    vtrans_k<<<dim3(32, 16), 256, 0, stream>>>(vT, vTt);
    band_mfma_k<<<dim3(16, 16, 32), 256, 0, stream>>>(qT, kT, posk, posq, c2p, p2c);
    attn_mfma_k<<<dim3(32, 16, 2), 256, 0, stream>>>(qT, kT, vTt, c2p, p2c, amask, flags, Opart, ml);
    combine_k<<<dim3(32, 16), 256, 0, stream>>>(Opart, ml, out);
}